// Round 8
// baseline (150.430 us; speedup 1.0000x reference)
//
#include <hip/hip_runtime.h>
#include <math.h>

#define B 8
#define SQ 128
#define SK 128
#define IVD 32
#define DIM 32
#define EV 64
#define H 8
#define NH 128
#define DK 8
#define TQ 2
#define KG 8      // k-groups in weighted-sum phase (16 k each)

__device__ __forceinline__ float fast_tanh(float x) {
    const float xc = fminf(fmaxf(x, -10.f), 10.f);
    const float t = __expf(2.f * xc);
    return (t - 1.f) / (t + 1.f);
}

// Shared-memory overlays (union keeps static LDS at the attn path's 46.5 KB so
// 3 blocks/CU fit; deadlock-impossibility proof relies on this).
struct AttnSmem {
    float  qs[TQ * EV];               // pre-scaled q rows
    float  sc[TQ * H * SK];           // exp'd scores (8 KB)
    float2 part[TQ * H * KG * DIM];   // PV partials (32 KB)
    float  xr[TQ * H * DIM];          // attn out rows (2 KB)
    float  ypart[4][TQ * NH];         // 4-way y partials (4 KB)
};
struct ProjSmem {                      // 4 teams x 2 rows
    float xs[4][2][IVD];
    float h1[4][2][NH];
    float ev[4][2][EV];
    float part[4][2][128];
};
struct ImpSmem {                       // 4 teams x 2 rows
    float xs2[4][2][IVD / 2];
    float h1b[4][2][NH];
    float red[4][2][2];
};

// Single launch, specialized blocks (512 threads each):
//   [0,128)    q-proj, 4 teams x 2 rows  -> qproj(ws), flag[blk]
//   [128,256)  k-proj, 4 teams x 2 rows  -> kproj(ws), flag[blk]
//   [256,384)  impute, 4 teams x 2 rows  -> qd
//   [384,896)  attn, 2 q rows; spins on its batch's 16 k-flags + 1 q-flag,
//              then reads kproj/qproj via relaxed agent atomic loads only.
// Progress proof: LDS 46.5 KB -> max 3 blocks/CU. Only the 512 attn blocks
// spin; 512 < 3*256, so some CU always has <=2 spinners -> >=66 KB free ->
// a producer block can always be scheduled. No deadlock for any dispatch order.
__global__ __launch_bounds__(512, 4) void fused_spin(
    const float* __restrict__ qv, const float* __restrict__ kv,
    const float* __restrict__ value, const int* __restrict__ mask,
    const float* __restrict__ imp,
    const float* __restrict__ w1, const float* __restrict__ b1,
    const float* __restrict__ w2,
    const float* __restrict__ wq, const float* __restrict__ bqv,
    const float* __restrict__ wk, const float* __restrict__ bkv,
    const float* __restrict__ wo, const float* __restrict__ bo,
    const float* __restrict__ wd1, const float* __restrict__ bd1,
    const float* __restrict__ ln_g, const float* __restrict__ ln_b,
    const float* __restrict__ wd2, const float* __restrict__ bd2,
    float* __restrict__ y, float* __restrict__ qd,
    float* __restrict__ qproj, float* __restrict__ kproj,
    unsigned long long* __restrict__ flags)
{
    const int blk = blockIdx.x;           // 0..895
    const int tid = threadIdx.x;          // 0..511

    // sentinel: two DIFFERENT 32-bit halves -> cannot alias any repeated
    // 32-bit poison fill pattern in the workspace.
    const unsigned long long MAGIC = 0x85EBCA6B9E3779B9ull;

    __shared__ __align__(16) char smem[sizeof(AttnSmem)];

    if (blk < 256) {
        // ================= projection blocks (q or k), round-0 arithmetic ====
        ProjSmem& S = *reinterpret_cast<ProjSmem*>(smem);
        const int team = tid >> 7, t = tid & 127;
        const int row0 = (blk & 127) * 8 + team * 2;
        const float* src; const float* wp; const float* bp; float* dst;
        if (blk < 128) { src = qv; wp = wq; bp = bqv; dst = qproj; }
        else           { src = kv; wp = wk; bp = bkv; dst = kproj; }

        if (t < 2 * IVD) S.xs[team][t >> 5][t & 31] = src[row0 * IVD + t];
        __syncthreads();

        // GEMV1: h1 = tanh(x @ w1 + b1)
        {
            float a0 = b1[t], a1 = a0;
            #pragma unroll
            for (int i = 0; i < IVD; ++i) {
                const float w = w1[i * NH + t];
                a0 += S.xs[team][0][i] * w; a1 += S.xs[team][1][i] * w;
            }
            S.h1[team][0][t] = fast_tanh(a0);
            S.h1[team][1][t] = fast_tanh(a1);
        }
        __syncthreads();

        const int o = t & 63, hf = t >> 6;
        // GEMV2: ev = h1 @ w2 (dot split in 2 halves)
        {
            float c0 = 0.f, c1 = 0.f;
            #pragma unroll 8
            for (int i = hf * 64; i < hf * 64 + 64; ++i) {
                const float w = w2[i * EV + o];
                c0 += S.h1[team][0][i] * w; c1 += S.h1[team][1][i] * w;
            }
            S.part[team][0][t] = c0; S.part[team][1][t] = c1;
        }
        __syncthreads();
        {
            const int row = t >> 6, oo = t & 63;
            S.ev[team][row][oo] = S.part[team][row][oo] + S.part[team][row][oo + 64];
        }
        __syncthreads();
        // GEMV3: dst = ev @ wp + bp
        {
            float c0 = 0.f, c1 = 0.f;
            #pragma unroll 8
            for (int j = hf * 32; j < hf * 32 + 32; ++j) {
                const float w = wp[j * EV + o];
                c0 += S.ev[team][0][j] * w; c1 += S.ev[team][1][j] * w;
            }
            S.part[team][0][t] = c0; S.part[team][1][t] = c1;
        }
        __syncthreads();
        {
            const int row = t >> 6, oo = t & 63;
            dst[(row0 + row) * EV + oo] =
                S.part[team][row][oo] + S.part[team][row][oo + 64] + bp[oo];
        }
        // publish: barrier drains all teams' stores, then one release + flag
        __syncthreads();
        if (tid == 0) {
            __builtin_amdgcn_fence(__ATOMIC_RELEASE, "agent");
            __hip_atomic_store(&flags[blk], MAGIC, __ATOMIC_RELAXED,
                               __HIP_MEMORY_SCOPE_AGENT);
        }
    } else if (blk < 384) {
        // ================= impute blocks (round-0 arithmetic) ================
        ImpSmem& S = *reinterpret_cast<ImpSmem*>(smem);
        const int team = tid >> 7, t = tid & 127;
        const int bs0 = (blk - 256) * 8 + team * 2;

        if (t < IVD) S.xs2[team][t >> 4][t & 15] = imp[bs0 * (IVD / 2) + t];
        __syncthreads();
        float a0 = bd1[t], a1 = a0;
        #pragma unroll
        for (int i = 0; i < IVD / 2; ++i) {
            const float w = wd1[i * NH + t];
            a0 += S.xs2[team][0][i] * w; a1 += S.xs2[team][1][i] * w;
        }

        float s0 = a0, s1 = a1;
        #pragma unroll
        for (int off = 32; off > 0; off >>= 1) {
            s0 += __shfl_down(s0, off, 64);
            s1 += __shfl_down(s1, off, 64);
        }
        if ((t & 63) == 0) { S.red[team][0][t >> 6] = s0; S.red[team][1][t >> 6] = s1; }
        __syncthreads();
        const float mu0 = (S.red[team][0][0] + S.red[team][0][1]) * (1.f / NH);
        const float mu1 = (S.red[team][1][0] + S.red[team][1][1]) * (1.f / NH);
        const float d0 = a0 - mu0, d1 = a1 - mu1;
        float t0 = d0 * d0, t1 = d1 * d1;
        __syncthreads();
        #pragma unroll
        for (int off = 32; off > 0; off >>= 1) {
            t0 += __shfl_down(t0, off, 64);
            t1 += __shfl_down(t1, off, 64);
        }
        if ((t & 63) == 0) { S.red[team][0][t >> 6] = t0; S.red[team][1][t >> 6] = t1; }
        __syncthreads();
        const float v0 = (S.red[team][0][0] + S.red[team][0][1]) * (1.f / NH);
        const float v1 = (S.red[team][1][0] + S.red[team][1][1]) * (1.f / NH);

        const float g = ln_g[t], bb = ln_b[t];
        S.h1b[team][0][t] = fmaxf(d0 * rsqrtf(v0 + 1e-5f) * g + bb, 0.f);
        S.h1b[team][1][t] = fmaxf(d1 * rsqrtf(v1 + 1e-5f) * g + bb, 0.f);
        __syncthreads();

        float c0 = bd2[t], c1 = c0;
        #pragma unroll 8
        for (int j = 0; j < NH; ++j) {
            const float w = wd2[j * NH + t];
            c0 += S.h1b[team][0][j] * w; c1 += S.h1b[team][1][j] * w;
        }
        qd[bs0 * NH + t] = c0;
        qd[(bs0 + 1) * NH + t] = c1;
    } else {
        // ================= attention blocks =================
        AttnSmem& S = *reinterpret_cast<AttnSmem*>(smem);
        const int a = blk - 384;              // 0..511
        const int b = a >> 6;                 // batch
        const int q0 = (a & 63) * TQ;

        // PV ownership: q-half = tid>>8, k-group = (tid>>5)&7, d = tid&31
        const int d = tid & 31, kg = (tid >> 5) & 7, qh = tid >> 8;

        // early private loads (inputs, cache-coherent): latency hides under spin
        float4 vv[4], mq[4];
        {
            const float* vb = value + b * SK * DIM + d;
            const int*   mb = mask  + b * SK * DIM + d;
            #pragma unroll
            for (int j = 0; j < 4; ++j) {
                const int k0 = kg * 16 + j * 4;
                const float m0 = (float)mb[(k0 + 0) * DIM];
                const float m1 = (float)mb[(k0 + 1) * DIM];
                const float m2 = (float)mb[(k0 + 2) * DIM];
                const float m3 = (float)mb[(k0 + 3) * DIM];
                mq[j] = make_float4(m0, m1, m2, m3);
                vv[j] = make_float4(vb[(k0 + 0) * DIM] * m0,
                                    vb[(k0 + 1) * DIM] * m1,
                                    vb[(k0 + 2) * DIM] * m2,
                                    vb[(k0 + 3) * DIM] * m3);
            }
        }

        // ---- spin: 16 k-flags of this batch + 1 q-flag (own row pair) ----
        {
            const unsigned long long* kf = flags + 128 + b * 16;
            const unsigned long long* qf = flags + b * 16 + ((a & 63) >> 2);
            const int lane = tid & 63;
            for (int it = 0; it < (1 << 22); ++it) {   // bounded: fail visibly
                unsigned long long v = MAGIC;
                if (lane < 16)
                    v = __hip_atomic_load(&kf[lane], __ATOMIC_RELAXED,
                                          __HIP_MEMORY_SCOPE_AGENT);
                else if (lane == 16)
                    v = __hip_atomic_load(qf, __ATOMIC_RELAXED,
                                          __HIP_MEMORY_SCOPE_AGENT);
                if (__all(v == MAGIC)) break;
                __builtin_amdgcn_s_sleep(1);
            }
            asm volatile("" ::: "memory");   // compiler-only: keep loads below
        }

        // qs staging via coherence-point loads (producer data, skip stale L1/L2)
        if (tid < TQ * EV) {
            const float qv8 = __hip_atomic_load(
                qproj + (b * SQ + q0) * EV + tid, __ATOMIC_RELAXED,
                __HIP_MEMORY_SCOPE_AGENT);
            S.qs[tid] = qv8 * 0.3535533905932738f;
        }
        __syncthreads();

        // scores -> exp (association order identical to verified round-4 path)
        #pragma unroll
        for (int i = 0; i < (TQ * H * SK) / 512; ++i) {
            const int p = tid + i * 512;
            const int q = p >> 10, rem = p & 1023, h = rem >> 7, k = rem & 127;
            const float* kr = kproj + (b * SK + k) * EV + h * DK;
            float kf[8];
            #pragma unroll
            for (int j = 0; j < 8; ++j)
                kf[j] = __hip_atomic_load(kr + j, __ATOMIC_RELAXED,
                                          __HIP_MEMORY_SCOPE_AGENT);
            const float4* qq = (const float4*)(S.qs + q * EV + h * DK);
            const float4 qa = qq[0], qb = qq[1];
            const float s = qa.x * kf[0] + qa.y * kf[1] + qa.z * kf[2] + qa.w * kf[3]
                          + qb.x * kf[4] + qb.y * kf[5] + qb.z * kf[6] + qb.w * kf[7];
            S.sc[p] = __expf(s);
        }
        __syncthreads();

        // PV: thread (qh, kg, d) -> num/den over its 16 k, all 8 heads
        #pragma unroll
        for (int h = 0; h < H; ++h) {
            const float4* sp = (const float4*)&S.sc[(qh * H + h) * SK + kg * 16];
            float num = 0.f, den = 0.f;
            #pragma unroll
            for (int j = 0; j < 4; ++j) {
                const float4 s = sp[j];
                num += s.x * vv[j].x + s.y * vv[j].y + s.z * vv[j].z + s.w * vv[j].w;
                den += s.x * mq[j].x + s.y * mq[j].y + s.z * mq[j].z + s.w * mq[j].w;
            }
            S.part[((qh * H + h) * KG + kg) * DIM + d] = make_float2(num, den);
        }
        __syncthreads();
        {   // reduce 8 k-groups
            const int h2 = (tid >> 5) & 7;
            float num = 0.f, den = 0.f;
            #pragma unroll
            for (int g = 0; g < KG; ++g) {
                const float2 p2 = S.part[((qh * H + h2) * KG + g) * DIM + d];
                num += p2.x; den += p2.y;
            }
            S.xr[qh * (H * DIM) + h2 * DIM + d] = num / den;
        }
        __syncthreads();

        // y = x @ wo + bo : 256-dot split in quarters
        {
            const int n = tid & 127, quarter = tid >> 7;
            const float* wop = wo + quarter * 64 * NH + n;
            const float* x0 = S.xr + quarter * 64;
            const float* x1 = S.xr + (H * DIM) + quarter * 64;
            float a0 = 0.f, a1 = 0.f;
            #pragma unroll 4
            for (int j = 0; j < 64; ++j) {
                const float w = wop[j * NH];
                a0 += w * x0[j];
                a1 += w * x1[j];
            }
            S.ypart[quarter][0 * NH + n] = a0;
            S.ypart[quarter][1 * NH + n] = a1;
        }
        __syncthreads();
        if (tid < TQ * NH) {
            const int q = tid >> 7, n = tid & 127;
            y[(b * SQ + q0 + q) * NH + n] =
                (S.ypart[0][q * NH + n] + S.ypart[1][q * NH + n])
              + (S.ypart[2][q * NH + n] + S.ypart[3][q * NH + n]) + bo[n];
        }
    }
}

extern "C" void kernel_launch(void* const* d_in, const int* in_sizes, int n_in,
                              void* d_out, int out_size, void* d_ws, size_t ws_size,
                              hipStream_t stream) {
    const float* query_value = (const float*)d_in[0];
    const float* key_value   = (const float*)d_in[1];
    const float* value       = (const float*)d_in[2];
    const float* impute      = (const float*)d_in[3];
    const int*   emb_mask    = (const int*)d_in[4];
    const float* w1   = (const float*)d_in[5];
    const float* b1   = (const float*)d_in[6];
    const float* w2   = (const float*)d_in[7];
    const float* wq   = (const float*)d_in[8];
    const float* bq   = (const float*)d_in[9];
    const float* wk   = (const float*)d_in[10];
    const float* bk   = (const float*)d_in[11];
    const float* wo   = (const float*)d_in[12];
    const float* bo   = (const float*)d_in[13];
    const float* wd1  = (const float*)d_in[14];
    const float* bd1  = (const float*)d_in[15];
    const float* ln_g = (const float*)d_in[16];
    const float* ln_b = (const float*)d_in[17];
    const float* wd2  = (const float*)d_in[18];
    const float* bd2  = (const float*)d_in[19];

    float* y  = (float*)d_out;                 // (B,SQ,NH)
    float* qd = y + B * SQ * NH;               // (B,SQ,NH)

    float* qproj = (float*)d_ws;               // (B,SQ,EV)
    float* kproj = qproj + B * SQ * EV;        // (B,SK,EV)
    unsigned long long* flags =
        (unsigned long long*)(kproj + B * SK * EV);  // 256 flags

    hipLaunchKernelGGL(fused_spin, dim3(896), dim3(512), 0, stream,
                       query_value, key_value, value, emb_mask, impute,
                       w1, b1, w2, wq, bq, wk, bk, wo, bo,
                       wd1, bd1, ln_g, ln_b, wd2, bd2,
                       y, qd, qproj, kproj, flags);
}

// Round 9
// 113.159 us; speedup vs baseline: 1.3294x; 1.3294x over previous
//
#include <hip/hip_runtime.h>
#include <math.h>

#define B 8
#define SQ 128
#define SK 128
#define IVD 32
#define DIM 32
#define EV 64
#define H 8
#define NH 128
#define DK 8
#define TQ 2
#define KG 8      // k-groups in weighted-sum phase (16 k each)

__device__ __forceinline__ float fast_tanh(float x) {
    const float xc = fminf(fmaxf(x, -10.f), 10.f);
    const float t = __expf(2.f * xc);
    return (t - 1.f) / (t + 1.f);
}

// ---------------- Kernel 1: q/k projections + impute, 2 rows per block --------
// (verbatim round-0/round-5 verified arithmetic)
// blocks [0,512)    : q-row pairs
// blocks [512,1024) : k-row pairs
// blocks [1024,1536): impute-row pairs
__global__ __launch_bounds__(128) void fused1_kernel(
    const float* __restrict__ qv, const float* __restrict__ kv,
    const float* __restrict__ w1, const float* __restrict__ b1,
    const float* __restrict__ w2,
    const float* __restrict__ wq, const float* __restrict__ bqv,
    const float* __restrict__ wk, const float* __restrict__ bkv,
    float* __restrict__ qout, float* __restrict__ kout,
    const float* __restrict__ imp,
    const float* __restrict__ wd1, const float* __restrict__ bd1,
    const float* __restrict__ ln_g, const float* __restrict__ ln_b,
    const float* __restrict__ wd2, const float* __restrict__ bd2,
    float* __restrict__ qd)
{
    const int r = blockIdx.x;
    const int tid = threadIdx.x;

    if (r < 1024) {
        __shared__ float xs[2][IVD];
        __shared__ float h1[2][NH];
        __shared__ float ev[2][EV];
        __shared__ float part[2][128];
        const float* src; const float* wp; const float* bp; float* dst;
        int row0;
        if (r < 512) { row0 = r * 2;         src = qv; wp = wq; bp = bqv; dst = qout; }
        else         { row0 = (r - 512) * 2; src = kv; wp = wk; bp = bkv; dst = kout; }

        if (tid < 2 * IVD) xs[tid >> 5][tid & 31] = src[row0 * IVD + tid];
        __syncthreads();

        {
            float a0 = b1[tid], a1 = a0;
            #pragma unroll
            for (int i = 0; i < IVD; ++i) {
                const float w = w1[i * NH + tid];
                a0 += xs[0][i] * w; a1 += xs[1][i] * w;
            }
            h1[0][tid] = fast_tanh(a0);
            h1[1][tid] = fast_tanh(a1);
        }
        __syncthreads();

        const int o = tid & 63, hf = tid >> 6;
        {
            float c0 = 0.f, c1 = 0.f;
            #pragma unroll 8
            for (int i = hf * 64; i < hf * 64 + 64; ++i) {
                const float w = w2[i * EV + o];
                c0 += h1[0][i] * w; c1 += h1[1][i] * w;
            }
            part[0][tid] = c0; part[1][tid] = c1;
        }
        __syncthreads();
        {
            const int row = tid >> 6, oo = tid & 63;
            ev[row][oo] = part[row][oo] + part[row][oo + 64];
        }
        __syncthreads();
        {
            float c0 = 0.f, c1 = 0.f;
            #pragma unroll 8
            for (int j = hf * 32; j < hf * 32 + 32; ++j) {
                const float w = wp[j * EV + o];
                c0 += ev[0][j] * w; c1 += ev[1][j] * w;
            }
            part[0][tid] = c0; part[1][tid] = c1;
        }
        __syncthreads();
        {
            const int row = tid >> 6, oo = tid & 63;
            dst[(row0 + row) * EV + oo] = part[row][oo] + part[row][oo + 64] + bp[oo];
        }
    } else {
        const int bs0 = (r - 1024) * 2;
        __shared__ float xs2[2][IVD / 2];
        __shared__ float h1b[2][NH];
        __shared__ float red[2][2];

        if (tid < IVD) xs2[tid >> 4][tid & 15] = imp[bs0 * (IVD / 2) + tid];
        __syncthreads();
        float a0 = bd1[tid], a1 = a0;
        #pragma unroll
        for (int i = 0; i < IVD / 2; ++i) {
            const float w = wd1[i * NH + tid];
            a0 += xs2[0][i] * w; a1 += xs2[1][i] * w;
        }

        float s0 = a0, s1 = a1;
        #pragma unroll
        for (int off = 32; off > 0; off >>= 1) {
            s0 += __shfl_down(s0, off, 64);
            s1 += __shfl_down(s1, off, 64);
        }
        if ((tid & 63) == 0) { red[0][tid >> 6] = s0; red[1][tid >> 6] = s1; }
        __syncthreads();
        const float mu0 = (red[0][0] + red[0][1]) * (1.f / NH);
        const float mu1 = (red[1][0] + red[1][1]) * (1.f / NH);
        const float d0 = a0 - mu0, d1 = a1 - mu1;
        float t0 = d0 * d0, t1 = d1 * d1;
        __syncthreads();
        #pragma unroll
        for (int off = 32; off > 0; off >>= 1) {
            t0 += __shfl_down(t0, off, 64);
            t1 += __shfl_down(t1, off, 64);
        }
        if ((tid & 63) == 0) { red[0][tid >> 6] = t0; red[1][tid >> 6] = t1; }
        __syncthreads();
        const float v0 = (red[0][0] + red[0][1]) * (1.f / NH);
        const float v1 = (red[1][0] + red[1][1]) * (1.f / NH);

        const float g = ln_g[tid], bb = ln_b[tid];
        h1b[0][tid] = fmaxf(d0 * rsqrtf(v0 + 1e-5f) * g + bb, 0.f);
        h1b[1][tid] = fmaxf(d1 * rsqrtf(v1 + 1e-5f) * g + bb, 0.f);
        __syncthreads();

        float c0 = bd2[tid], c1 = c0;
        #pragma unroll 8
        for (int j = 0; j < NH; ++j) {
            const float w = wd2[j * NH + tid];
            c0 += h1b[0][j] * w; c1 += h1b[1][j] * w;
        }
        qd[bs0 * NH + tid] = c0;
        qd[(bs0 + 1) * NH + tid] = c1;
    }
}

// ---------------- Kernel 2: masked-softmax attention + output GEMV ------------
// 512 blocks x 512 threads (2 blocks/CU = 16 waves/CU). No LDS value/mask
// staging: each thread holds its private (d, kg) slice in registers. PV dot
// and reduce orders bitwise-identical to the verified round-0 kernel.
__global__ __launch_bounds__(512, 4) void attn_kernel(
    const float* __restrict__ qproj, const float* __restrict__ kproj,
    const float* __restrict__ value, const int* __restrict__ mask,
    const float* __restrict__ wo, const float* __restrict__ bo,
    float* __restrict__ y)
{
    const int blk = blockIdx.x;
    const int b = blk >> 6;               // 64 blocks per batch (SQ/TQ)
    const int q0 = (blk & 63) * TQ;
    const int tid = threadIdx.x;          // 0..511

    __shared__ __align__(16) float qs[TQ * EV];              // pre-scaled q rows
    __shared__ __align__(16) float sc[TQ * H * SK];          // exp'd scores (8 KB)
    __shared__ __align__(16) float2 part[TQ * H * KG * DIM]; // PV partials (32 KB)
    __shared__ __align__(16) float xr[TQ * H * DIM];         // attn out rows (2 KB)
    __shared__ __align__(16) float ypart[4][TQ * NH];        // 4-way y partials (4 KB)

    // PV ownership: q-half = tid>>8, k-group = (tid>>5)&7, d = tid&31
    const int d = tid & 31, kg = (tid >> 5) & 7, qh = tid >> 8;

    // early private loads: value/mask 16-k slice -> registers (issued first so
    // latency overlaps the qs load and scores phase)
    float4 vv[4], mq[4];
    {
        const float* vb = value + b * SK * DIM + d;
        const int*   mb = mask  + b * SK * DIM + d;
        #pragma unroll
        for (int j = 0; j < 4; ++j) {
            const int k0 = kg * 16 + j * 4;
            const float m0 = (float)mb[(k0 + 0) * DIM];
            const float m1 = (float)mb[(k0 + 1) * DIM];
            const float m2 = (float)mb[(k0 + 2) * DIM];
            const float m3 = (float)mb[(k0 + 3) * DIM];
            mq[j] = make_float4(m0, m1, m2, m3);
            vv[j] = make_float4(vb[(k0 + 0) * DIM] * m0,
                                vb[(k0 + 1) * DIM] * m1,
                                vb[(k0 + 2) * DIM] * m2,
                                vb[(k0 + 3) * DIM] * m3);
        }
    }

    if (tid < TQ * EV) qs[tid] = qproj[(b * SQ + q0) * EV + tid] * 0.3535533905932738f;
    __syncthreads();

    // scores -> exp (identical arithmetic/order to round 0; 4 dots per thread)
    #pragma unroll
    for (int i = 0; i < (TQ * H * SK) / 512; ++i) {
        const int p = tid + i * 512;
        const int q = p >> 10, rem = p & 1023, h = rem >> 7, k = rem & 127;
        const float4* kr = (const float4*)(kproj + (b * SK + k) * EV + h * DK);
        const float4* qq = (const float4*)(qs + q * EV + h * DK);
        const float4 k0 = kr[0], k1 = kr[1], qa = qq[0], qb = qq[1];
        const float s = qa.x * k0.x + qa.y * k0.y + qa.z * k0.z + qa.w * k0.w
                      + qb.x * k1.x + qb.y * k1.y + qb.z * k1.z + qb.w * k1.w;
        sc[p] = __expf(s);
    }
    __syncthreads();

    // PV: thread (qh, kg, d) computes num/den over its 16 k for all 8 heads of
    // its q-half — dot order identical to round 0.
    #pragma unroll
    for (int h = 0; h < H; ++h) {
        const float4* sp = (const float4*)&sc[(qh * H + h) * SK + kg * 16];
        float num = 0.f, den = 0.f;
        #pragma unroll
        for (int j = 0; j < 4; ++j) {
            const float4 s = sp[j];
            num += s.x * vv[j].x + s.y * vv[j].y + s.z * vv[j].z + s.w * vv[j].w;
            den += s.x * mq[j].x + s.y * mq[j].y + s.z * mq[j].z + s.w * mq[j].w;
        }
        part[((qh * H + h) * KG + kg) * DIM + d] = make_float2(num, den);
    }
    __syncthreads();
    {   // reduce 8 k-groups; thread -> (q = tid>>8, h = (tid>>5)&7, d = tid&31)
        const int h2 = (tid >> 5) & 7;
        float num = 0.f, den = 0.f;
        #pragma unroll
        for (int g = 0; g < KG; ++g) {
            const float2 p2 = part[((qh * H + h2) * KG + g) * DIM + d];
            num += p2.x; den += p2.y;
        }
        xr[qh * (H * DIM) + h2 * DIM + d] = num / den;
    }
    __syncthreads();

    // y = x @ wo + bo : 256-dot split in quarters, wo load shared across TQ rows
    {
        const int n = tid & 127, quarter = tid >> 7;
        const float* wop = wo + quarter * 64 * NH + n;
        const float* x0 = xr + quarter * 64;
        const float* x1 = xr + (H * DIM) + quarter * 64;
        float a0 = 0.f, a1 = 0.f;
        #pragma unroll 4
        for (int j = 0; j < 64; ++j) {
            const float w = wop[j * NH];
            a0 += w * x0[j];
            a1 += w * x1[j];
        }
        ypart[quarter][0 * NH + n] = a0;
        ypart[quarter][1 * NH + n] = a1;
    }
    __syncthreads();
    if (tid < TQ * NH) {
        const int q = tid >> 7, n = tid & 127;
        y[(b * SQ + q0 + q) * NH + n] =
            (ypart[0][q * NH + n] + ypart[1][q * NH + n])
          + (ypart[2][q * NH + n] + ypart[3][q * NH + n]) + bo[n];
    }
}

extern "C" void kernel_launch(void* const* d_in, const int* in_sizes, int n_in,
                              void* d_out, int out_size, void* d_ws, size_t ws_size,
                              hipStream_t stream) {
    const float* query_value = (const float*)d_in[0];
    const float* key_value   = (const float*)d_in[1];
    const float* value       = (const float*)d_in[2];
    const float* impute      = (const float*)d_in[3];
    const int*   emb_mask    = (const int*)d_in[4];
    const float* w1   = (const float*)d_in[5];
    const float* b1   = (const float*)d_in[6];
    const float* w2   = (const float*)d_in[7];
    const float* wq   = (const float*)d_in[8];
    const float* bq   = (const float*)d_in[9];
    const float* wk   = (const float*)d_in[10];
    const float* bk   = (const float*)d_in[11];
    const float* wo   = (const float*)d_in[12];
    const float* bo   = (const float*)d_in[13];
    const float* wd1  = (const float*)d_in[14];
    const float* bd1  = (const float*)d_in[15];
    const float* ln_g = (const float*)d_in[16];
    const float* ln_b = (const float*)d_in[17];
    const float* wd2  = (const float*)d_in[18];
    const float* bd2  = (const float*)d_in[19];

    float* y  = (float*)d_out;                 // (B,SQ,NH)
    float* qd = y + B * SQ * NH;               // (B,SQ,NH)

    float* qproj = (float*)d_ws;               // (B,SQ,EV)
    float* kproj = qproj + B * SQ * EV;        // (B,SK,EV)

    hipLaunchKernelGGL(fused1_kernel, dim3(1536), dim3(128), 0, stream,
                       query_value, key_value, w1, b1, w2, wq, bq, wk, bk,
                       qproj, kproj,
                       impute, wd1, bd1, ln_g, ln_b, wd2, bd2, qd);
    hipLaunchKernelGGL(attn_kernel, dim3(B * SQ / TQ), dim3(512), 0, stream,
                       qproj, kproj, value, emb_mask, wo, bo, y);
}